// Round 4
// baseline (267.402 us; speedup 1.0000x reference)
//
#include <hip/hip_runtime.h>

#define NATOMS 20000
#define NCHAN  64
#define K2 120
#define TILES 8                   // 16-atom tiles per wave; block = 512 atoms

// ws layout (bytes):
//   [0        .. 524288)  W2bf bf16[64][4096]  c*4096 + x*256 + (y*16+i)
//   [524288   .. 557056)  W1bf bf16[64][256]   c*256 + x*16 + y
//   [557056   .. 559104)  W0bf bf16[64][16]    c*16 + x
//   [559104   .. 5679104) out_T f32[64][20000] (optional, if ws_size allows)
#define W1_OFF_B 524288
#define W0_OFF_B 557056
#define OT_OFF_B 559104
#define WS_NEED  (OT_OFF_B + (size_t)NCHAN * NATOMS * 4)

typedef __attribute__((ext_vector_type(8))) short bf16x8;
typedef __attribute__((ext_vector_type(4))) float f32x4;

__device__ inline short f2bf_rne(float x) {
    union { float f; unsigned u; } v; v.f = x;
    unsigned r = v.u + 0x7FFF + ((v.u >> 16) & 1);
    return (short)(r >> 16);
}
// pack two f32 -> packed bf16 (round-half-up): low16 = a, high16 = b
__device__ inline unsigned pk_bf(float a, float b) {
    unsigned au = __float_as_uint(a) + 0x8000u;
    unsigned bu = __float_as_uint(b) + 0x8000u;
    return __builtin_amdgcn_perm(bu, au, 0x07060302u);
}
// DPP butterfly add over 16-lane rows: xor1, xor2, half_mirror, mirror
#define DPP_ADD(x, ctrl) ((x) + __uint_as_float((unsigned)__builtin_amdgcn_update_dpp( \
        0, (int)__float_as_uint(x), (ctrl), 0xF, 0xF, true)))

// ---------------------------------------------------------------------------
// Kernel 1: fold weights -> bf16 per-channel tensors. 1092 blocks, 4368 waves.
// W2 part: wave = one xyi row (U2 reads wave-uniform broadcast), lane = channel
// (w2 reads 256B coalesced, L1-resident). 4 independent FMA chains.
// ---------------------------------------------------------------------------
__global__ __launch_bounds__(256) void precompute_kernel(
    const float* __restrict__ U2, const float* __restrict__ U1,
    const float* __restrict__ U0, const float* __restrict__ w2,
    const float* __restrict__ w1, const float* __restrict__ w0,
    void* __restrict__ wsv)
{
    short* W2bf = (short*)wsv;
    short* W1bf = (short*)((char*)wsv + W1_OFF_B);
    short* W0bf = (short*)((char*)wsv + W0_OFF_B);
    const int b = blockIdx.x, t = threadIdx.x;

    if (b < 1024) {
        const int row = b * 4 + (t >> 6);         // 0..4095, uniform per wave
        const int c   = t & 63;
        const float* u = U2 + (size_t)row * K2;
        float a0 = 0.f, a1 = 0.f, a2 = 0.f, a3 = 0.f;
        #pragma unroll 6
        for (int k = 0; k < K2; k += 4) {
            a0 += u[k]     * w2[(k)     * NCHAN + c];
            a1 += u[k + 1] * w2[(k + 1) * NCHAN + c];
            a2 += u[k + 2] * w2[(k + 2) * NCHAN + c];
            a3 += u[k + 3] * w2[(k + 3) * NCHAN + c];
        }
        W2bf[c * 4096 + row] = f2bf_rne((a0 + a1) + (a2 + a3));
    } else if (b < 1088) {
        const int id = (b - 1024) * 256 + t;      // 16384 = 64c x 256xy
        const int c = id >> 8, xy = id & 255;
        const float* u = U1 + xy * 8;
        float a = 0.f;
        #pragma unroll
        for (int k = 0; k < 8; ++k) a += u[k] * w1[k * NCHAN + c];
        W1bf[c * 256 + xy] = f2bf_rne(a);
    } else {
        const int id = (b - 1088) * 256 + t;      // 1024 = 64c x 16x
        const int c = id >> 4, x = id & 15;
        const float* u = U0 + x * 4;
        float a = 0.f;
        #pragma unroll
        for (int k = 0; k < 4; ++k) a += u[k] * w0[k * NCHAN + c];
        W0bf[c * 16 + x] = f2bf_rne(a);
    }
}

// ---------------------------------------------------------------------------
// Kernel 2: out[n,c] = sum_x f_x * D[n,x], D = MFMA(P, W2ext),
//   P[n, k=(y,i)] = f_y*f_i, K = 256 + 16(W1) + 1(W0) -> 288 (9 MFMAs/tile).
// Block = 1 channel x 512 atoms. B-fragments loaded ONCE per wave from global
// (coalesced, L2-resident) -> no LDS staging, no barrier, no bank conflicts.
// Output goes to out_T[c][n] (contiguous per block) to avoid the 48x write
// amplification of 4B strided stores into out[n][c].
// ---------------------------------------------------------------------------
__global__ __launch_bounds__(256) void contract_kernel(
    const float* __restrict__ nf,   // [N, 64, 16]
    const void* __restrict__ wsv,
    float* __restrict__ outT,       // [64][NATOMS] (in ws) -- if use_t
    float* __restrict__ out,        // [N, 64]              -- if !use_t
    int use_t)
{
    const short* W2g = (const short*)wsv;
    const short* W1g = (const short*)((const char*)wsv + W1_OFF_B);
    const short* W0g = (const short*)((const char*)wsv + W0_OFF_B);

    __shared__ float Fs[4][16][20];               // per-wave f tile [atom][i]

    const int c = blockIdx.y, tid = threadIdx.x;
    const int wave = tid >> 6, lane = tid & 63;
    const int m = lane & 15, q = lane >> 4;

    // --- B fragments straight from global, resident for the whole block ---
    const short* Wc = W2g + (size_t)c * 4096;
    bf16x8 bfr[8];
    #pragma unroll
    for (int ch = 0; ch < 8; ++ch)                // 1KB/wave per ch, coalesced
        bfr[ch] = *(const bf16x8*)&Wc[m * 256 + ch * 32 + q * 8];
    bf16x8 b8 = (bf16x8)0;                        // W1 row (k'<16) + W0 (k'=16)
    if (q < 2) b8 = *(const bf16x8*)&W1g[c * 256 + m * 16 + q * 8];
    if (q == 2) b8[0] = W0g[c * 16 + m];

    const int aBase = blockIdx.x * (TILES * 64);

    #pragma unroll 1
    for (int t = 0; t < TILES; ++t) {
        const int a0 = aBase + (wave * TILES + t) * 16;
        const int n_at = a0 + m;

        float f[16];
        if (n_at < NATOMS) {
            const float4* fp = (const float4*)(nf + ((size_t)n_at * NCHAN + c) * 16);
            #pragma unroll
            for (int j = 0; j < 4; ++j) {
                float4 v = fp[j];
                f[4*j] = v.x; f[4*j+1] = v.y; f[4*j+2] = v.z; f[4*j+3] = v.w;
            }
        } else {
            #pragma unroll
            for (int j = 0; j < 16; ++j) f[j] = 0.f;
        }
        if (q == 0) {                             // stage f for epilogue x-read
            #pragma unroll
            for (int j = 0; j < 4; ++j)
                *(float4*)&Fs[wave][m][j*4] = (float4){f[4*j], f[4*j+1], f[4*j+2], f[4*j+3]};
        }

        float fi8[8];                             // f[(q&1)*8 + j]
        #pragma unroll
        for (int j = 0; j < 8; ++j) fi8[j] = (q & 1) ? f[8 + j] : f[j];

        // chunk-8 A frag: q<2 -> f[q*8+j] (x W1); q==2,j==0 -> 1.0 (x W0)
        uint4 a8w;
        a8w.x = pk_bf(fi8[0], fi8[1]); a8w.y = pk_bf(fi8[2], fi8[3]);
        a8w.z = pk_bf(fi8[4], fi8[5]); a8w.w = pk_bf(fi8[6], fi8[7]);
        if (q >= 2) { a8w.x = (q == 2) ? 0x3F80u : 0u; a8w.y = 0; a8w.z = 0; a8w.w = 0; }

        f32x4 accA = {0.f,0.f,0.f,0.f}, accB = {0.f,0.f,0.f,0.f};
        accA = __builtin_amdgcn_mfma_f32_16x16x32_bf16(
                   __builtin_bit_cast(bf16x8, a8w), b8, accA, 0, 0, 0);
        #pragma unroll
        for (int ch = 0; ch < 8; ++ch) {
            // P[k] = f_y * f_i ; y = ch*2 + (q>>1), i = (q&1)*8 + j
            float fy = (q & 2) ? f[2*ch + 1] : f[2*ch];
            uint4 aw;
            aw.x = pk_bf(fy * fi8[0], fy * fi8[1]);
            aw.y = pk_bf(fy * fi8[2], fy * fi8[3]);
            aw.z = pk_bf(fy * fi8[4], fy * fi8[5]);
            aw.w = pk_bf(fy * fi8[6], fy * fi8[7]);
            bf16x8 af = __builtin_bit_cast(bf16x8, aw);
            if (ch & 1) accB = __builtin_amdgcn_mfma_f32_16x16x32_bf16(af, bfr[ch], accB, 0, 0, 0);
            else        accA = __builtin_amdgcn_mfma_f32_16x16x32_bf16(af, bfr[ch], accA, 0, 0, 0);
        }
        f32x4 acc = accA + accB;

        // --- epilogue: out[n] = sum_x f[n,x]*D[n,x]; D row=q*4+r, col=m ---
        float tr[4];
        #pragma unroll
        for (int r = 0; r < 4; ++r) {
            float v = Fs[wave][q*4 + r][m] * acc[r];
            v = DPP_ADD(v, 0xB1);     // xor1
            v = DPP_ADD(v, 0x4E);     // xor2
            v = DPP_ADD(v, 0x141);    // xor7  (row_half_mirror)
            v = DPP_ADD(v, 0x140);    // xor15 (row_mirror)
            tr[r] = v;
        }
        if (use_t) {
            if (m == 0 && a0 + q * 4 < NATOMS) {  // NATOMS%4==0 -> whole f4 valid
                float4 v = {tr[0], tr[1], tr[2], tr[3]};
                *(float4*)&outT[(size_t)c * NATOMS + a0 + q * 4] = v;
            }
        } else {
            if (m == 0) {
                #pragma unroll
                for (int r = 0; r < 4; ++r) {
                    int n = a0 + q * 4 + r;
                    if (n < NATOMS) out[(size_t)n * NCHAN + c] = tr[r];
                }
            }
        }
    }
}

// ---------------------------------------------------------------------------
// Kernel 3: out_T[64][N] -> out[N][64] via 64x64 LDS tiles. All global reads
// and writes are >=256B contiguous per 4-thread group.
// ---------------------------------------------------------------------------
__global__ __launch_bounds__(256) void transpose_kernel(
    const float* __restrict__ outT, float* __restrict__ out)
{
    __shared__ float T[64][65];
    const int t = threadIdx.x;
    const int n0 = blockIdx.x * 64;

    const int cr = t >> 2, seg = t & 3;           // read: row=c, 4 f4/thread
    #pragma unroll
    for (int j = 0; j < 4; ++j) {
        int nl = seg * 16 + j * 4;
        int n = n0 + nl;
        if (n < NATOMS) {
            float4 v = *(const float4*)&outT[(size_t)cr * NATOMS + n];
            *(float4*)&T[cr][nl] = v;
        }
    }
    __syncthreads();

    const int nl = t >> 2, cs = t & 3;            // write: row=n, 4 f4/thread
    const int n = n0 + nl;
    if (n < NATOMS) {
        #pragma unroll
        for (int j = 0; j < 4; ++j) {
            int c0 = cs * 16 + j * 4;
            float4 v = {T[c0][nl], T[c0+1][nl], T[c0+2][nl], T[c0+3][nl]};
            *(float4*)&out[(size_t)n * NCHAN + c0] = v;
        }
    }
}

extern "C" void kernel_launch(void* const* d_in, const int* in_sizes, int n_in,
                              void* d_out, int out_size, void* d_ws, size_t ws_size,
                              hipStream_t stream)
{
    const float* nf = (const float*)d_in[0];
    const float* U2 = (const float*)d_in[1];
    const float* U1 = (const float*)d_in[2];
    const float* U0 = (const float*)d_in[3];
    const float* w2 = (const float*)d_in[4];
    const float* w1 = (const float*)d_in[5];
    const float* w0 = (const float*)d_in[6];
    float* out  = (float*)d_out;
    float* outT = (float*)((char*)d_ws + OT_OFF_B);
    const int use_t = (ws_size >= WS_NEED) ? 1 : 0;

    precompute_kernel<<<1092, 256, 0, stream>>>(U2, U1, U0, w2, w1, w0, d_ws);

    dim3 grid((NATOMS + TILES * 64 - 1) / (TILES * 64), NCHAN);   // (40, 64)
    contract_kernel<<<grid, 256, 0, stream>>>(nf, d_ws, outT, out, use_t);

    if (use_t)
        transpose_kernel<<<(NATOMS + 63) / 64, 256, 0, stream>>>(outT, out);
}